// Round 5
// baseline (178.503 us; speedup 1.0000x reference)
//
#include <hip/hip_runtime.h>
#include <hip/hip_bf16.h>

// ---------------------------------------------------------------------------
// AlsoDecoder, folded + fp16 MFMA, Q computed on the fly:
//   x1 = S[col] + (also_pts[row]@W_p + b_in)      (S precomputed fp16;
//                                                  Q rebuilt per edge from
//                                                  12B of L2-resident pts)
//   y  = relu(x1) @ W1 + b1                       (mfma 16x16x32 f16, swapped
//                                                  operands: edge = lane&15)
//   logits = relu(y) @ (W2@W_out) + (b2@W_out+b_out)    (layer 3 folded)
//   probs = softmax(logits)
// W1 frags staged in LDS (8KB, stride-16B ds_read_b128 = conflict-free);
// W_p/b_in frags + packed-half2 wfold in registers; fold via v_pk_fma_f16.
// ---------------------------------------------------------------------------

typedef _Float16 half8 __attribute__((ext_vector_type(8)));
typedef _Float16 half2v __attribute__((ext_vector_type(2)));
typedef __attribute__((ext_vector_type(4))) float f32x4;

union U84h { uint4 u; half8 h; };
union UW01 { uint4 u; _Float16 h[8]; };
union UPH  { half2v h; int i; };

__device__ __forceinline__ half8 relu8(half8 v) {
    half8 z;
#pragma unroll
    for (int i = 0; i < 8; ++i) z[i] = (_Float16)0.f;
    return __builtin_elementwise_max(v, z);
}
__device__ __forceinline__ half8 splat8(float v) {
    _Float16 h = (_Float16)v;
    half8 r = {h, h, h, h, h, h, h, h};
    return r;
}

// ---------------- prep: S table -------------------------------------------
// S[p][c*16..c*16+15] = feats[p]@W_f - pcd[p]@W_p ; 4 threads/point (c=0..3),
// feats float4 loads shared via L1 within the quad.
__global__ __launch_bounds__(256) void precompute_S(
    const float* __restrict__ feats, const float* __restrict__ pcd,
    const float* __restrict__ w_in, _Float16* __restrict__ S, int N) {
    int p = blockIdx.x * 64 + (threadIdx.x >> 2);
    int c = threadIdx.x & 3;
    if (p >= N) return;
    const float4* f4 = (const float4*)(feats + (size_t)p * 64);
    float4 a0 = {0.f,0.f,0.f,0.f}, a1 = a0, a2 = a0, a3 = a0;
#pragma unroll
    for (int kq = 0; kq < 16; ++kq) {
        float4 fv = f4[kq];
        float fvs[4] = {fv.x, fv.y, fv.z, fv.w};
#pragma unroll
        for (int s = 0; s < 4; ++s) {
            int k = kq * 4 + s;
            const float4* wr = (const float4*)(w_in + k * 64 + c * 16);
            float4 w0 = wr[0], w1 = wr[1], w2 = wr[2], w3 = wr[3];
            float fx = fvs[s];
            a0.x = fmaf(fx, w0.x, a0.x); a0.y = fmaf(fx, w0.y, a0.y);
            a0.z = fmaf(fx, w0.z, a0.z); a0.w = fmaf(fx, w0.w, a0.w);
            a1.x = fmaf(fx, w1.x, a1.x); a1.y = fmaf(fx, w1.y, a1.y);
            a1.z = fmaf(fx, w1.z, a1.z); a1.w = fmaf(fx, w1.w, a1.w);
            a2.x = fmaf(fx, w2.x, a2.x); a2.y = fmaf(fx, w2.y, a2.y);
            a2.z = fmaf(fx, w2.z, a2.z); a2.w = fmaf(fx, w2.w, a2.w);
            a3.x = fmaf(fx, w3.x, a3.x); a3.y = fmaf(fx, w3.y, a3.y);
            a3.z = fmaf(fx, w3.z, a3.z); a3.w = fmaf(fx, w3.w, a3.w);
        }
    }
    const float* pp = pcd + (size_t)p * 3;
#pragma unroll
    for (int d = 0; d < 3; ++d) {
        float fx = -pp[d];
        const float4* wr = (const float4*)(w_in + (64 + d) * 64 + c * 16);
        float4 w0 = wr[0], w1 = wr[1], w2 = wr[2], w3 = wr[3];
        a0.x = fmaf(fx, w0.x, a0.x); a0.y = fmaf(fx, w0.y, a0.y);
        a0.z = fmaf(fx, w0.z, a0.z); a0.w = fmaf(fx, w0.w, a0.w);
        a1.x = fmaf(fx, w1.x, a1.x); a1.y = fmaf(fx, w1.y, a1.y);
        a1.z = fmaf(fx, w1.z, a1.z); a1.w = fmaf(fx, w1.w, a1.w);
        a2.x = fmaf(fx, w2.x, a2.x); a2.y = fmaf(fx, w2.y, a2.y);
        a2.z = fmaf(fx, w2.z, a2.z); a2.w = fmaf(fx, w2.w, a2.w);
        a3.x = fmaf(fx, w3.x, a3.x); a3.y = fmaf(fx, w3.y, a3.y);
        a3.z = fmaf(fx, w3.z, a3.z); a3.w = fmaf(fx, w3.w, a3.w);
    }
    union { uint4 u; _Float16 h[8]; } o0, o1;
    o0.h[0]=(_Float16)a0.x; o0.h[1]=(_Float16)a0.y; o0.h[2]=(_Float16)a0.z; o0.h[3]=(_Float16)a0.w;
    o0.h[4]=(_Float16)a1.x; o0.h[5]=(_Float16)a1.y; o0.h[6]=(_Float16)a1.z; o0.h[7]=(_Float16)a1.w;
    o1.h[0]=(_Float16)a2.x; o1.h[1]=(_Float16)a2.y; o1.h[2]=(_Float16)a2.z; o1.h[3]=(_Float16)a2.w;
    o1.h[4]=(_Float16)a3.x; o1.h[5]=(_Float16)a3.y; o1.h[6]=(_Float16)a3.z; o1.h[7]=(_Float16)a3.w;
    _Float16* dst = S + (size_t)p * 64 + c * 16;
    *(uint4*)dst = o0.u;
    *(uint4*)(dst + 8) = o1.u;
}

// ---------------- prep: pack weights --------------------------------------
// w1f: W1 in A-frag order (f=ntile*2+ks; k=ks*32+8*(lane>>4)+j; n=ntile*16+(lane&15))
// wpf: W_p rows in B-frag k-slot order; bqf: b_in likewise.
// w01f: half2(wfold0[n], wfold1[n]); bf: folded bias.
__global__ __launch_bounds__(256) void pack_fold(
    const float* __restrict__ w1, const float* __restrict__ w_in,
    const float* __restrict__ b_in, const float* __restrict__ w2,
    const float* __restrict__ w_out, const float* __restrict__ b2,
    const float* __restrict__ b_out,
    _Float16* __restrict__ w1f, _Float16* __restrict__ wpf,
    _Float16* __restrict__ bqf, _Float16* __restrict__ w01f,
    float* __restrict__ bf) {
    int t = blockIdx.x * 256 + threadIdx.x;
    if (t < 4096) {
        int f = t >> 9, lane = (t >> 3) & 63, j = t & 7;
        int ntile = f >> 1, kstep = f & 1;
        int k = kstep * 32 + ((lane >> 4) << 3) + j;
        int n = ntile * 16 + (lane & 15);
        w1f[t] = (_Float16)w1[k * 64 + n];
    } else if (t < 7168) {
        int i = t - 4096;                       // d*1024 + ks*512 + lane*8 + j
        int d = i >> 10, ks = (i >> 9) & 1, lane = (i >> 3) & 63, j = i & 7;
        int k = ks * 32 + ((lane >> 4) << 3) + j;
        wpf[i] = (_Float16)w_in[(64 + d) * 64 + k];
    } else if (t < 8192) {
        int i = t - 7168;                       // ks*512 + lane*8 + j
        int ks = i >> 9, lane = (i >> 3) & 63, j = i & 7;
        int k = ks * 32 + ((lane >> 4) << 3) + j;
        bqf[i] = (_Float16)b_in[k];
    } else if (t < 8256) {
        int n = t - 8192;
        float s0 = 0.f, s1 = 0.f;
#pragma unroll
        for (int j = 0; j < 64; ++j) {
            s0 = fmaf(w2[n * 64 + j], w_out[j * 2 + 0], s0);
            s1 = fmaf(w2[n * 64 + j], w_out[j * 2 + 1], s1);
        }
        w01f[2 * n]     = (_Float16)s0;
        w01f[2 * n + 1] = (_Float16)s1;
    } else if (t == 8256) {
        float s0 = b_out[0], s1 = b_out[1];
#pragma unroll
        for (int j = 0; j < 64; ++j) {
            s0 = fmaf(b2[j], w_out[j * 2 + 0], s0);
            s1 = fmaf(b2[j], w_out[j * 2 + 1], s1);
        }
        bf[0] = s0; bf[1] = s1;
    }
}

// ---------------- edge kernel --------------------------------------------
__global__ __launch_bounds__(256, 4) void edge_mfma(
    const _Float16* __restrict__ S, const float* __restrict__ also_pts,
    const int* __restrict__ row, const int* __restrict__ col,
    const int* __restrict__ labels,
    const half8* __restrict__ w1f, const half8* __restrict__ wpf,
    const half8* __restrict__ bqf, const uint4* __restrict__ w01f,
    const float* __restrict__ bfold, const float* __restrict__ b1,
    float* __restrict__ out, int E, int ngroups) {
    __shared__ half8 wf_lds[8][64];
    {
        int t = threadIdx.x;
        wf_lds[t >> 6][t & 63] = w1f[t];
        wf_lds[(t + 256) >> 6][t & 63] = w1f[t + 256];
    }
    __syncthreads();

    int lane = threadIdx.x & 63;
    int idx  = lane & 15;          // edge-in-group (D col)
    int g    = lane >> 4;
    int gwave  = blockIdx.x * 4 + (threadIdx.x >> 6);
    int nwaves = gridDim.x * 4;

    // per-lane constant fragments (registers, loop-invariant)
    half8 wpd[3][2];
#pragma unroll
    for (int d = 0; d < 3; ++d)
#pragma unroll
        for (int ks = 0; ks < 2; ++ks) wpd[d][ks] = wpf[(d * 2 + ks) * 64 + lane];
    half8 bq0 = bqf[lane], bq1 = bqf[64 + lane];
    uint4 w01v[4];
    f32x4 b1v[4];
#pragma unroll
    for (int tt = 0; tt < 4; ++tt) {
        w01v[tt] = w01f[tt * 4 + g];
        b1v[tt]  = *(const f32x4*)(b1 + tt * 16 + 4 * g);
    }
    float bf0 = bfold[0], bf1 = bfold[1];

    for (int grp = gwave; grp < ngroups; grp += nwaves) {
        int base = grp << 4;
        int e = base + idx;
        bool eok = (e < E);
        int es = eok ? e : (E - 1);
        int r = row[es];
        int c = col[es];

        // S gather (2x16B per lane) + Q on the fly from also_pts (L2-resident)
        const uint4* sp = (const uint4*)(S + (size_t)c * 64);
        U84h s0, s1;
        s0.u = sp[g];
        s1.u = sp[4 + g];
        const float* ap = also_pts + (size_t)r * 3;
        half8 axv = splat8(ap[0]), ayv = splat8(ap[1]), azv = splat8(ap[2]);
        half8 q0 = bq0 + axv * wpd[0][0] + ayv * wpd[1][0] + azv * wpd[2][0];
        half8 q1 = bq1 + axv * wpd[0][1] + ayv * wpd[1][1] + azv * wpd[2][1];
        half8 x0 = relu8(s0.h + q0);
        half8 x1 = relu8(s1.h + q1);

        // Y = W1'·X (+b1): lane holds Y[n=tt*16+4g+reg][edge=idx]
        f32x4 acc[4];
#pragma unroll
        for (int tt = 0; tt < 4; ++tt) {
            acc[tt] = __builtin_amdgcn_mfma_f32_16x16x32_f16(wf_lds[2 * tt][lane],     x0, b1v[tt], 0, 0, 0);
            acc[tt] = __builtin_amdgcn_mfma_f32_16x16x32_f16(wf_lds[2 * tt + 1][lane], x1, acc[tt], 0, 0, 0);
        }

        // logits fold: both classes per op via v_pk_fma_f16
        half2v p = {(_Float16)0.f, (_Float16)0.f};
#pragma unroll
        for (int tt = 0; tt < 4; ++tt) {
            UW01 wv; wv.u = w01v[tt];
#pragma unroll
            for (int reg = 0; reg < 4; ++reg) {
                _Float16 yh = (_Float16)fmaxf(acc[tt][reg], 0.f);
                half2v y2 = {yh, yh};
                half2v w2 = {wv.h[2 * reg], wv.h[2 * reg + 1]};
                p += y2 * w2;
            }
        }
        UPH pu; pu.h = p;
        UPH o;
        o.i = __shfl_xor(pu.i, 16); pu.h += o.h;
        o.i = __shfl_xor(pu.i, 32); pu.h += o.h;

        if (g == 0 && eok) {
            float l0 = (float)pu.h[0] + bf0;
            float l1 = (float)pu.h[1] + bf1;
            float mx = fmaxf(l0, l1);
            float e0 = __expf(l0 - mx);
            float e1 = __expf(l1 - mx);
            float inv = 1.f / (e0 + e1);
            *(float2*)(out + (size_t)e * 2) = make_float2(e0 * inv, e1 * inv);
            out[(size_t)2 * E + e] = (float)labels[r];
        }
    }
}

extern "C" void kernel_launch(void* const* d_in, const int* in_sizes, int n_in,
                              void* d_out, int out_size, void* d_ws, size_t ws_size,
                              hipStream_t stream) {
    const float* pcd      = (const float*)d_in[0];
    const float* feats    = (const float*)d_in[1];
    const float* also_pts = (const float*)d_in[2];
    const int*   labels   = (const int*)d_in[3];
    const int*   row      = (const int*)d_in[4];
    const int*   col      = (const int*)d_in[5];
    const float* w_in     = (const float*)d_in[6];
    const float* b_in     = (const float*)d_in[7];
    const float* w1       = (const float*)d_in[8];
    const float* b1       = (const float*)d_in[9];
    const float* w2       = (const float*)d_in[10];
    const float* b2       = (const float*)d_in[11];
    const float* w_out    = (const float*)d_in[12];
    const float* b_out    = (const float*)d_in[13];

    int N = in_sizes[0] / 3;
    int M = in_sizes[2] / 3;
    (void)M;
    int E = in_sizes[4];

    _Float16* Sb  = (_Float16*)d_ws;
    _Float16* w1f = Sb + (size_t)N * 64;
    _Float16* wpf = w1f + 4096;
    _Float16* bqf = wpf + 3072;
    _Float16* w01 = bqf + 1024;
    float*    bf  = (float*)(w01 + 128);

    precompute_S<<<(N + 63) / 64, 256, 0, stream>>>(feats, pcd, w_in, Sb, N);
    pack_fold<<<33, 256, 0, stream>>>(w1, w_in, b_in, w2, w_out, b2, b_out,
                                      w1f, wpf, bqf, w01, bf);

    int ngroups = (E + 15) / 16;
    edge_mfma<<<2048, 256, 0, stream>>>(Sb, also_pts, row, col, labels,
                                        (const half8*)w1f, (const half8*)wpf,
                                        (const half8*)bqf, (const uint4*)w01,
                                        bf, b1, (float*)d_out, E, ngroups);
}

// Round 6
// 84.628 us; speedup vs baseline: 2.1093x; 2.1093x over previous
//
#include <hip/hip_runtime.h>
#include <hip/hip_bf16.h>

// ---------------------------------------------------------------------------
// AlsoDecoder, folded + fp16 MFMA end-to-end:
//   S[p] = feats[p]@W_f - pcd[p]@W_p        (MFMA prep kernel, fp16 table)
//   x1 = S[col] + (also_pts[row]@W_p + b_in)   (Q rebuilt per edge, L2-resident)
//   y  = relu(x1) @ W1 + b1                    (mfma 16x16x32 f16, swapped)
//   logits = relu(y) @ (W2@W_out) + (b2@W_out+b_out)    (layer 3 folded)
//   probs = softmax(logits)
// ---------------------------------------------------------------------------

typedef _Float16 half8 __attribute__((ext_vector_type(8)));
typedef _Float16 half2v __attribute__((ext_vector_type(2)));
typedef __attribute__((ext_vector_type(4))) float f32x4;

union U84h { uint4 u; half8 h; };
union UW01 { uint4 u; _Float16 h[8]; };
union UPH  { half2v h; int i; };

__device__ __forceinline__ half8 relu8(half8 v) {
    half8 z;
#pragma unroll
    for (int i = 0; i < 8; ++i) z[i] = (_Float16)0.f;
    return __builtin_elementwise_max(v, z);
}
__device__ __forceinline__ half8 splat8(float v) {
    _Float16 h = (_Float16)v;
    half8 r = {h, h, h, h, h, h, h, h};
    return r;
}

// ---------------- prep: pack weights --------------------------------------
// w1f : W1 in A-frag order for the edge kernel.
// wAf : [12 frags] A-frag weights for S-prep: ntile*3+ks; ks 0/1 = W_f rows,
//       ks 2 = -W_p rows in k-slots j<3 of chunk 0, zeros elsewhere.
// wpf : W_p rows in B-frag k-slot order (edge Q rebuild); bqf: b_in likewise.
// w01f: half2(wfold0[n], wfold1[n]); bf: folded output bias.
__global__ __launch_bounds__(256) void pack_fold(
    const float* __restrict__ w1, const float* __restrict__ w_in,
    const float* __restrict__ b_in, const float* __restrict__ w2,
    const float* __restrict__ w_out, const float* __restrict__ b2,
    const float* __restrict__ b_out,
    _Float16* __restrict__ w1f, _Float16* __restrict__ wAf,
    _Float16* __restrict__ wpf, _Float16* __restrict__ bqf,
    _Float16* __restrict__ w01f, float* __restrict__ bf) {
    int t = blockIdx.x * 256 + threadIdx.x;
    if (t < 4096) {
        int f = t >> 9, lane = (t >> 3) & 63, j = t & 7;
        int ntile = f >> 1, kstep = f & 1;
        int k = kstep * 32 + ((lane >> 4) << 3) + j;
        int n = ntile * 16 + (lane & 15);
        w1f[t] = (_Float16)w1[k * 64 + n];
    } else if (t < 10240) {
        int i = t - 4096;
        int f = i >> 9, lane = (i >> 3) & 63, j = i & 7;
        int ntile = f / 3, ks = f % 3;
        int n = ntile * 16 + (lane & 15);
        float v;
        if (ks < 2) {
            int k = ks * 32 + ((lane >> 4) << 3) + j;
            v = w_in[k * 64 + n];
        } else {
            v = ((lane >> 4) == 0 && j < 3) ? -w_in[(64 + j) * 64 + n] : 0.f;
        }
        wAf[i] = (_Float16)v;
    } else if (t < 13312) {
        int i = t - 10240;                      // d*1024 + ks*512 + lane*8 + j
        int d = i >> 10, ks = (i >> 9) & 1, lane = (i >> 3) & 63, j = i & 7;
        int k = ks * 32 + ((lane >> 4) << 3) + j;
        wpf[i] = (_Float16)w_in[(64 + d) * 64 + k];
    } else if (t < 14336) {
        int i = t - 13312;                      // ks*512 + lane*8 + j
        int ks = i >> 9, lane = (i >> 3) & 63, j = i & 7;
        int k = ks * 32 + ((lane >> 4) << 3) + j;
        bqf[i] = (_Float16)b_in[k];
    } else if (t < 14400) {
        int n = t - 14336;
        float s0 = 0.f, s1 = 0.f;
#pragma unroll
        for (int j = 0; j < 64; ++j) {
            s0 = fmaf(w2[n * 64 + j], w_out[j * 2 + 0], s0);
            s1 = fmaf(w2[n * 64 + j], w_out[j * 2 + 1], s1);
        }
        w01f[2 * n]     = (_Float16)s0;
        w01f[2 * n + 1] = (_Float16)s1;
    } else if (t == 14400) {
        float s0 = b_out[0], s1 = b_out[1];
#pragma unroll
        for (int j = 0; j < 64; ++j) {
            s0 = fmaf(b2[j], w_out[j * 2 + 0], s0);
            s1 = fmaf(b2[j], w_out[j * 2 + 1], s1);
        }
        bf[0] = s0; bf[1] = s1;
    }
}

// ---------------- prep: S table via MFMA -----------------------------------
// One wave per 16 points. D[row=n][col=point]; 12 MFMAs (4 ntiles x 3 ksteps).
__global__ __launch_bounds__(256) void precompute_S(
    const float* __restrict__ feats, const float* __restrict__ pcd,
    const half8* __restrict__ wAf, _Float16* __restrict__ S, int N) {
    int lane = threadIdx.x & 63;
    int idx = lane & 15, g = lane >> 4;
    int base = (blockIdx.x * 4 + (threadIdx.x >> 6)) * 16;
    if (base >= N) return;

    half8 wa[12];
#pragma unroll
    for (int f = 0; f < 12; ++f) wa[f] = wAf[f * 64 + lane];

    int p = base + idx;
    int ps = p < N ? p : N - 1;
    const float4* fp = (const float4*)(feats + (size_t)ps * 64);
    float4 f0 = fp[2 * g], f1 = fp[2 * g + 1];         // k = 8g..8g+7   (ks0)
    float4 f2 = fp[8 + 2 * g], f3 = fp[8 + 2 * g + 1]; // k = 32+8g..    (ks1)
    half8 b0, b1, b2;
    b0[0]=(_Float16)f0.x; b0[1]=(_Float16)f0.y; b0[2]=(_Float16)f0.z; b0[3]=(_Float16)f0.w;
    b0[4]=(_Float16)f1.x; b0[5]=(_Float16)f1.y; b0[6]=(_Float16)f1.z; b0[7]=(_Float16)f1.w;
    b1[0]=(_Float16)f2.x; b1[1]=(_Float16)f2.y; b1[2]=(_Float16)f2.z; b1[3]=(_Float16)f2.w;
    b1[4]=(_Float16)f3.x; b1[5]=(_Float16)f3.y; b1[6]=(_Float16)f3.z; b1[7]=(_Float16)f3.w;
    float px = 0.f, py = 0.f, pz = 0.f;
    if (g == 0) {
        const float* pp = pcd + (size_t)ps * 3;
        px = pp[0]; py = pp[1]; pz = pp[2];
    }
#pragma unroll
    for (int i = 0; i < 8; ++i) b2[i] = (_Float16)0.f;
    b2[0] = (_Float16)px; b2[1] = (_Float16)py; b2[2] = (_Float16)pz;

    f32x4 zero = {0.f, 0.f, 0.f, 0.f};
#pragma unroll
    for (int tt = 0; tt < 4; ++tt) {
        f32x4 acc;
        acc = __builtin_amdgcn_mfma_f32_16x16x32_f16(wa[tt * 3 + 0], b0, zero, 0, 0, 0);
        acc = __builtin_amdgcn_mfma_f32_16x16x32_f16(wa[tt * 3 + 1], b1, acc, 0, 0, 0);
        acc = __builtin_amdgcn_mfma_f32_16x16x32_f16(wa[tt * 3 + 2], b2, acc, 0, 0, 0);
        union { uint2 u; _Float16 h[4]; } o;
        o.h[0] = (_Float16)acc[0]; o.h[1] = (_Float16)acc[1];
        o.h[2] = (_Float16)acc[2]; o.h[3] = (_Float16)acc[3];
        if (p < N) *(uint2*)(S + (size_t)p * 64 + tt * 16 + 4 * g) = o.u;
    }
}

// ---------------- edge kernel --------------------------------------------
__global__ __launch_bounds__(256, 4) void edge_mfma(
    const _Float16* __restrict__ S, const float* __restrict__ also_pts,
    const int* __restrict__ row, const int* __restrict__ col,
    const int* __restrict__ labels,
    const half8* __restrict__ w1f, const half8* __restrict__ wpf,
    const half8* __restrict__ bqf, const uint4* __restrict__ w01f,
    const float* __restrict__ bfold, const float* __restrict__ b1,
    float* __restrict__ out, int E, int ngroups) {
    __shared__ half8 wf_lds[8][64];
    {
        int t = threadIdx.x;
        wf_lds[t >> 6][t & 63] = w1f[t];
        wf_lds[(t + 256) >> 6][t & 63] = w1f[t + 256];
    }
    __syncthreads();

    int lane = threadIdx.x & 63;
    int idx  = lane & 15;          // edge-in-group (D col)
    int g    = lane >> 4;
    int gwave  = blockIdx.x * 4 + (threadIdx.x >> 6);
    int nwaves = gridDim.x * 4;

    half8 wpd[3][2];
#pragma unroll
    for (int d = 0; d < 3; ++d)
#pragma unroll
        for (int ks = 0; ks < 2; ++ks) wpd[d][ks] = wpf[(d * 2 + ks) * 64 + lane];
    half8 bq0 = bqf[lane], bq1 = bqf[64 + lane];
    uint4 w01v[4];
    f32x4 b1v[4];
#pragma unroll
    for (int tt = 0; tt < 4; ++tt) {
        w01v[tt] = w01f[tt * 4 + g];
        b1v[tt]  = *(const f32x4*)(b1 + tt * 16 + 4 * g);
    }
    float bf0 = bfold[0], bf1 = bfold[1];

    for (int grp = gwave; grp < ngroups; grp += nwaves) {
        int base = grp << 4;
        int e = base + idx;
        bool eok = (e < E);
        int es = eok ? e : (E - 1);
        int r = row[es];
        int c = col[es];

        const uint4* sp = (const uint4*)(S + (size_t)c * 64);
        U84h s0, s1;
        s0.u = sp[g];
        s1.u = sp[4 + g];
        const float* ap = also_pts + (size_t)r * 3;
        half8 axv = splat8(ap[0]), ayv = splat8(ap[1]), azv = splat8(ap[2]);
        half8 q0 = bq0 + axv * wpd[0][0] + ayv * wpd[1][0] + azv * wpd[2][0];
        half8 q1 = bq1 + axv * wpd[0][1] + ayv * wpd[1][1] + azv * wpd[2][1];
        half8 x0 = relu8(s0.h + q0);
        half8 x1 = relu8(s1.h + q1);

        f32x4 acc[4];
#pragma unroll
        for (int tt = 0; tt < 4; ++tt) {
            acc[tt] = __builtin_amdgcn_mfma_f32_16x16x32_f16(wf_lds[2 * tt][lane],     x0, b1v[tt], 0, 0, 0);
            acc[tt] = __builtin_amdgcn_mfma_f32_16x16x32_f16(wf_lds[2 * tt + 1][lane], x1, acc[tt], 0, 0, 0);
        }

        half2v p = {(_Float16)0.f, (_Float16)0.f};
#pragma unroll
        for (int tt = 0; tt < 4; ++tt) {
            UW01 wv; wv.u = w01v[tt];
#pragma unroll
            for (int reg = 0; reg < 4; ++reg) {
                _Float16 yh = (_Float16)fmaxf(acc[tt][reg], 0.f);
                half2v y2 = {yh, yh};
                half2v w2 = {wv.h[2 * reg], wv.h[2 * reg + 1]};
                p += y2 * w2;
            }
        }
        UPH pu; pu.h = p;
        UPH o;
        o.i = __shfl_xor(pu.i, 16); pu.h += o.h;
        o.i = __shfl_xor(pu.i, 32); pu.h += o.h;

        if (g == 0 && eok) {
            float l0 = (float)pu.h[0] + bf0;
            float l1 = (float)pu.h[1] + bf1;
            float mx = fmaxf(l0, l1);
            float e0 = __expf(l0 - mx);
            float e1 = __expf(l1 - mx);
            float inv = 1.f / (e0 + e1);
            *(float2*)(out + (size_t)e * 2) = make_float2(e0 * inv, e1 * inv);
            out[(size_t)2 * E + e] = (float)labels[r];
        }
    }
}

extern "C" void kernel_launch(void* const* d_in, const int* in_sizes, int n_in,
                              void* d_out, int out_size, void* d_ws, size_t ws_size,
                              hipStream_t stream) {
    const float* pcd      = (const float*)d_in[0];
    const float* feats    = (const float*)d_in[1];
    const float* also_pts = (const float*)d_in[2];
    const int*   labels   = (const int*)d_in[3];
    const int*   row      = (const int*)d_in[4];
    const int*   col      = (const int*)d_in[5];
    const float* w_in     = (const float*)d_in[6];
    const float* b_in     = (const float*)d_in[7];
    const float* w1       = (const float*)d_in[8];
    const float* b1       = (const float*)d_in[9];
    const float* w2       = (const float*)d_in[10];
    const float* b2       = (const float*)d_in[11];
    const float* w_out    = (const float*)d_in[12];
    const float* b_out    = (const float*)d_in[13];

    int N = in_sizes[0] / 3;
    int E = in_sizes[4];

    _Float16* Sb  = (_Float16*)d_ws;
    _Float16* w1f = Sb + (size_t)N * 64;
    _Float16* wAf = w1f + 4096;
    _Float16* wpf = wAf + 6144;
    _Float16* bqf = wpf + 3072;
    _Float16* w01 = bqf + 1024;
    float*    bf  = (float*)(w01 + 128);

    pack_fold<<<57, 256, 0, stream>>>(w1, w_in, b_in, w2, w_out, b2, b_out,
                                      w1f, wAf, wpf, bqf, w01, bf);

    int ngroupsS = (N + 15) / 16;
    precompute_S<<<(ngroupsS + 3) / 4, 256, 0, stream>>>(
        feats, pcd, (const half8*)wAf, Sb, N);

    int ngroups = (E + 15) / 16;
    edge_mfma<<<2048, 256, 0, stream>>>(Sb, also_pts, row, col, labels,
                                        (const half8*)w1f, (const half8*)wpf,
                                        (const half8*)bqf, (const uint4*)w01,
                                        bf, b1, (float*)d_out, E, ngroups);
}

// Round 8
// 81.829 us; speedup vs baseline: 2.1814x; 1.0342x over previous
//
#include <hip/hip_runtime.h>
#include <hip/hip_bf16.h>

// ---------------------------------------------------------------------------
// AlsoDecoder, folded + fp16 MFMA end-to-end, software-pipelined edge loop:
//   S[p] = feats[p]@W_f - pcd[p]@W_p + b_in   (MFMA prep kernel, fp16 table)
//   x1 = S[col] + also_pts[row]@W_p           (Q rebuilt per edge, L2-resident)
//   y  = relu(x1) @ W1                        (mfma 16x16x32 f16, swapped)
//   h2 = relu(y + b1)                         (packed-f16 fold epilogue)
//   logits = h2 @ (W2@W_out) + (b2@W_out+b_out)      (layer 3 folded)
//   probs = softmax(logits)
// Edge loop prefetches indices 2-ahead and gathers 1-ahead to hide the
// dependent index->gather latency chain under the compute body.
// ---------------------------------------------------------------------------

typedef _Float16 half8 __attribute__((ext_vector_type(8)));
typedef _Float16 half2v __attribute__((ext_vector_type(2)));
typedef __fp16   fp16x2 __attribute__((ext_vector_type(2)));
typedef __attribute__((ext_vector_type(4))) float f32x4;

union U84h { uint4 u; half8 h; };
union UPH  { half2v h; fp16x2 f; int i; unsigned u; };

__device__ __forceinline__ half2v cvt2h(float a, float b) {
    UPH t;
    t.f = __builtin_amdgcn_cvt_pkrtz(a, b);
    return t.h;
}

__device__ __forceinline__ half8 relu8(half8 v) {
    half8 z;
#pragma unroll
    for (int i = 0; i < 8; ++i) z[i] = (_Float16)0.f;
    return __builtin_elementwise_max(v, z);
}

// ---------------- prep: pack weights --------------------------------------
// w1f : W1 in A-frag order for the edge kernel.
// wAf : [12 frags] A-frag weights for S-prep (ks2 = -W_p rows, zero-padded).
// wpf : W_p rows in B-frag k-slot order (edge Q rebuild).
// w0h/w1h : wfold columns as half (packed-pair consumed); b1h : b1 as half.
// bf : folded output bias.
__global__ __launch_bounds__(256) void pack_fold(
    const float* __restrict__ w1, const float* __restrict__ w_in,
    const float* __restrict__ b1, const float* __restrict__ w2,
    const float* __restrict__ w_out, const float* __restrict__ b2,
    const float* __restrict__ b_out,
    _Float16* __restrict__ w1f, _Float16* __restrict__ wAf,
    _Float16* __restrict__ wpf, _Float16* __restrict__ w0h,
    _Float16* __restrict__ w1h, _Float16* __restrict__ b1h,
    float* __restrict__ bf) {
    int t = blockIdx.x * 256 + threadIdx.x;
    if (t < 4096) {
        int f = t >> 9, lane = (t >> 3) & 63, j = t & 7;
        int ntile = f >> 1, kstep = f & 1;
        int k = kstep * 32 + ((lane >> 4) << 3) + j;
        int n = ntile * 16 + (lane & 15);
        w1f[t] = (_Float16)w1[k * 64 + n];
    } else if (t < 10240) {
        int i = t - 4096;
        int f = i >> 9, lane = (i >> 3) & 63, j = i & 7;
        int ntile = f / 3, ks = f % 3;
        int n = ntile * 16 + (lane & 15);
        float v;
        if (ks < 2) {
            int k = ks * 32 + ((lane >> 4) << 3) + j;
            v = w_in[k * 64 + n];
        } else {
            v = ((lane >> 4) == 0 && j < 3) ? -w_in[(64 + j) * 64 + n] : 0.f;
        }
        wAf[i] = (_Float16)v;
    } else if (t < 13312) {
        int i = t - 10240;                      // d*1024 + ks*512 + lane*8 + j
        int d = i >> 10, ks = (i >> 9) & 1, lane = (i >> 3) & 63, j = i & 7;
        int k = ks * 32 + ((lane >> 4) << 3) + j;
        wpf[i] = (_Float16)w_in[(64 + d) * 64 + k];
    } else if (t < 13376) {
        int n = t - 13312;
        float s0 = 0.f, s1 = 0.f;
#pragma unroll
        for (int j = 0; j < 64; ++j) {
            s0 = fmaf(w2[n * 64 + j], w_out[j * 2 + 0], s0);
            s1 = fmaf(w2[n * 64 + j], w_out[j * 2 + 1], s1);
        }
        w0h[n] = (_Float16)s0;
        w1h[n] = (_Float16)s1;
    } else if (t < 13440) {
        int n = t - 13376;
        b1h[n] = (_Float16)b1[n];
    } else if (t == 13440) {
        float s0 = b_out[0], s1 = b_out[1];
#pragma unroll
        for (int j = 0; j < 64; ++j) {
            s0 = fmaf(b2[j], w_out[j * 2 + 0], s0);
            s1 = fmaf(b2[j], w_out[j * 2 + 1], s1);
        }
        bf[0] = s0; bf[1] = s1;
    }
}

// ---------------- prep: S table via MFMA -----------------------------------
// One wave per 16 points; C-init = b_in (absorbed into S).
__global__ __launch_bounds__(256) void precompute_S(
    const float* __restrict__ feats, const float* __restrict__ pcd,
    const float* __restrict__ b_in, const half8* __restrict__ wAf,
    _Float16* __restrict__ S, int N) {
    int lane = threadIdx.x & 63;
    int idx = lane & 15, g = lane >> 4;
    int base = (blockIdx.x * 4 + (threadIdx.x >> 6)) * 16;
    if (base >= N) return;

    half8 wa[12];
#pragma unroll
    for (int f = 0; f < 12; ++f) wa[f] = wAf[f * 64 + lane];

    int p = base + idx;
    int ps = p < N ? p : N - 1;
    const float4* fp = (const float4*)(feats + (size_t)ps * 64);
    float4 f0 = fp[2 * g], f1 = fp[2 * g + 1];
    float4 f2 = fp[8 + 2 * g], f3 = fp[8 + 2 * g + 1];
    half8 b0, b1v, b2v;
    b0[0]=(_Float16)f0.x; b0[1]=(_Float16)f0.y; b0[2]=(_Float16)f0.z; b0[3]=(_Float16)f0.w;
    b0[4]=(_Float16)f1.x; b0[5]=(_Float16)f1.y; b0[6]=(_Float16)f1.z; b0[7]=(_Float16)f1.w;
    b1v[0]=(_Float16)f2.x; b1v[1]=(_Float16)f2.y; b1v[2]=(_Float16)f2.z; b1v[3]=(_Float16)f2.w;
    b1v[4]=(_Float16)f3.x; b1v[5]=(_Float16)f3.y; b1v[6]=(_Float16)f3.z; b1v[7]=(_Float16)f3.w;
    float px = 0.f, py = 0.f, pz = 0.f;
    if (g == 0) {
        const float* pp = pcd + (size_t)ps * 3;
        px = pp[0]; py = pp[1]; pz = pp[2];
    }
#pragma unroll
    for (int i = 0; i < 8; ++i) b2v[i] = (_Float16)0.f;
    b2v[0] = (_Float16)px; b2v[1] = (_Float16)py; b2v[2] = (_Float16)pz;

#pragma unroll
    for (int tt = 0; tt < 4; ++tt) {
        f32x4 bi = *(const f32x4*)(b_in + tt * 16 + 4 * g);
        f32x4 acc;
        acc = __builtin_amdgcn_mfma_f32_16x16x32_f16(wa[tt * 3 + 0], b0, bi, 0, 0, 0);
        acc = __builtin_amdgcn_mfma_f32_16x16x32_f16(wa[tt * 3 + 1], b1v, acc, 0, 0, 0);
        acc = __builtin_amdgcn_mfma_f32_16x16x32_f16(wa[tt * 3 + 2], b2v, acc, 0, 0, 0);
        union { uint2 u; _Float16 h[4]; } o;
        o.h[0] = (_Float16)acc[0]; o.h[1] = (_Float16)acc[1];
        o.h[2] = (_Float16)acc[2]; o.h[3] = (_Float16)acc[3];
        if (p < N) *(uint2*)(S + (size_t)p * 64 + tt * 16 + 4 * g) = o.u;
    }
}

// ---------------- edge kernel --------------------------------------------
__global__ __launch_bounds__(256, 4) void edge_mfma(
    const _Float16* __restrict__ S, const float* __restrict__ also_pts,
    const int* __restrict__ row, const int* __restrict__ col,
    const int* __restrict__ labels,
    const half8* __restrict__ w1f, const half8* __restrict__ wpf,
    const unsigned* __restrict__ w0p, const unsigned* __restrict__ w1p,
    const unsigned* __restrict__ b1p, const float* __restrict__ bfold,
    float* __restrict__ out, int E, int ngroups) {
    __shared__ half8 wf_lds[8][64];
    {
        int t = threadIdx.x;
        wf_lds[t >> 6][t & 63] = w1f[t];
        wf_lds[(t + 256) >> 6][t & 63] = w1f[t + 256];
    }
    __syncthreads();

    int lane = threadIdx.x & 63;
    int idx  = lane & 15;          // edge-in-group (D col)
    int g    = lane >> 4;
    int gwave  = blockIdx.x * 4 + (threadIdx.x >> 6);
    int nwaves = gridDim.x * 4;
    if (gwave >= ngroups) return;

    // persistent per-lane constants
    half8 wpd[3][2];
#pragma unroll
    for (int d = 0; d < 3; ++d)
#pragma unroll
        for (int ks = 0; ks < 2; ++ks) wpd[d][ks] = wpf[(d * 2 + ks) * 64 + lane];
    UPH w0v[8], w1v[8], b1v[8];
#pragma unroll
    for (int tt = 0; tt < 4; ++tt)
#pragma unroll
        for (int h = 0; h < 2; ++h) {
            int i = tt * 8 + 2 * g + h;
            w0v[tt * 2 + h].u = w0p[i];
            w1v[tt * 2 + h].u = w1p[i];
            b1v[tt * 2 + h].u = b1p[i];
        }
    float bf0 = bfold[0], bf1 = bfold[1];
    half2v zero2 = {(_Float16)0.f, (_Float16)0.f};

    // ---- software pipeline: idx 2-ahead, gather 1-ahead ----
    int grp = gwave, stride = nwaves;
    int es0 = (grp << 4) + idx; es0 = es0 < E ? es0 : E - 1;
    int r_c = row[es0], c_c = col[es0];
    const uint4* sp0 = (const uint4*)(S + (size_t)c_c * 64);
    uint4 s0_c = sp0[g], s1_c = sp0[4 + g];
    const float* ap0 = also_pts + (size_t)r_c * 3;
    float ax_c = ap0[0], ay_c = ap0[1], az_c = ap0[2];
    int lb_c = labels[r_c];

    int gn = grp + stride; gn = gn < ngroups ? gn : grp;
    int es1 = (gn << 4) + idx; es1 = es1 < E ? es1 : E - 1;
    int r_n = row[es1], c_n = col[es1];

    for (; grp < ngroups; grp += stride) {
        // prefetch gathers for i+1
        const uint4* spn = (const uint4*)(S + (size_t)c_n * 64);
        uint4 s0_n = spn[g], s1_n = spn[4 + g];
        const float* apn = also_pts + (size_t)r_n * 3;
        float ax_n = apn[0], ay_n = apn[1], az_n = apn[2];
        int lb_n = labels[r_n];
        // prefetch indices for i+2
        int g2 = grp + 2 * stride; g2 = g2 < ngroups ? g2 : grp;
        int es2 = (g2 << 4) + idx; es2 = es2 < E ? es2 : E - 1;
        int r_2 = row[es2], c_2 = col[es2];

        // ---- compute current ----
        int e = (grp << 4) + idx;
        bool eok = e < E;
        U84h s0u, s1u; s0u.u = s0_c; s1u.u = s1_c;
        _Float16 ah = (_Float16)ax_c, bh = (_Float16)ay_c, ch = (_Float16)az_c;
        half8 av = {ah, ah, ah, ah, ah, ah, ah, ah};
        half8 bv = {bh, bh, bh, bh, bh, bh, bh, bh};
        half8 cv = {ch, ch, ch, ch, ch, ch, ch, ch};
        half8 q0 = av * wpd[0][0] + bv * wpd[1][0] + cv * wpd[2][0];
        half8 q1 = av * wpd[0][1] + bv * wpd[1][1] + cv * wpd[2][1];
        half8 x0 = relu8(s0u.h + q0);
        half8 x1 = relu8(s1u.h + q1);

        f32x4 zero = {0.f, 0.f, 0.f, 0.f};
        f32x4 acc[4];
#pragma unroll
        for (int tt = 0; tt < 4; ++tt) {
            acc[tt] = __builtin_amdgcn_mfma_f32_16x16x32_f16(wf_lds[2 * tt][lane],     x0, zero, 0, 0, 0);
            acc[tt] = __builtin_amdgcn_mfma_f32_16x16x32_f16(wf_lds[2 * tt + 1][lane], x1, acc[tt], 0, 0, 0);
        }

        // packed fold: h2 = relu(y + b1); p += h2 * wfold
        half2v p0 = zero2, p1 = zero2;
#pragma unroll
        for (int tt = 0; tt < 4; ++tt) {
            half2v h01 = cvt2h(acc[tt][0], acc[tt][1]);
            half2v h23 = cvt2h(acc[tt][2], acc[tt][3]);
            h01 = __builtin_elementwise_max(h01 + b1v[tt * 2 + 0].h, zero2);
            h23 = __builtin_elementwise_max(h23 + b1v[tt * 2 + 1].h, zero2);
            p0 += h01 * w0v[tt * 2 + 0].h + h23 * w0v[tt * 2 + 1].h;
            p1 += h01 * w1v[tt * 2 + 0].h + h23 * w1v[tt * 2 + 1].h;
        }
        UPH P0, P1, T;
        P0.h = p0; P1.h = p1;
        T.i = __shfl_xor(P0.i, 16); P0.h += T.h;
        T.i = __shfl_xor(P0.i, 32); P0.h += T.h;
        T.i = __shfl_xor(P1.i, 16); P1.h += T.h;
        T.i = __shfl_xor(P1.i, 32); P1.h += T.h;

        if (g == 0 && eok) {
            float l0 = (float)P0.h[0] + (float)P0.h[1] + bf0;
            float l1 = (float)P1.h[0] + (float)P1.h[1] + bf1;
            float mx = fmaxf(l0, l1);
            float e0 = __expf(l0 - mx);
            float e1 = __expf(l1 - mx);
            float inv = 1.f / (e0 + e1);
            *(float2*)(out + (size_t)e * 2) = make_float2(e0 * inv, e1 * inv);
            out[(size_t)2 * E + e] = (float)lb_c;
        }

        // rotate pipeline state
        s0_c = s0_n; s1_c = s1_n;
        ax_c = ax_n; ay_c = ay_n; az_c = az_n;
        lb_c = lb_n;
        r_n = r_2; c_n = c_2;
    }
}

extern "C" void kernel_launch(void* const* d_in, const int* in_sizes, int n_in,
                              void* d_out, int out_size, void* d_ws, size_t ws_size,
                              hipStream_t stream) {
    const float* pcd      = (const float*)d_in[0];
    const float* feats    = (const float*)d_in[1];
    const float* also_pts = (const float*)d_in[2];
    const int*   labels   = (const int*)d_in[3];
    const int*   row      = (const int*)d_in[4];
    const int*   col      = (const int*)d_in[5];
    const float* w_in     = (const float*)d_in[6];
    const float* b_in     = (const float*)d_in[7];
    const float* w1       = (const float*)d_in[8];
    const float* b1       = (const float*)d_in[9];
    const float* w2       = (const float*)d_in[10];
    const float* b2       = (const float*)d_in[11];
    const float* w_out    = (const float*)d_in[12];
    const float* b_out    = (const float*)d_in[13];

    int N = in_sizes[0] / 3;
    int E = in_sizes[4];

    _Float16* Sb  = (_Float16*)d_ws;
    _Float16* w1f = Sb + (size_t)N * 64;
    _Float16* wAf = w1f + 4096;
    _Float16* wpf = wAf + 6144;
    _Float16* w0h = wpf + 3072;
    _Float16* w1h = w0h + 64;
    _Float16* b1h = w1h + 64;
    float*    bf  = (float*)(b1h + 64);

    pack_fold<<<53, 256, 0, stream>>>(w1, w_in, b1, w2, w_out, b2, b_out,
                                      w1f, wAf, wpf, w0h, w1h, b1h, bf);

    int ngroupsS = (N + 15) / 16;
    precompute_S<<<(ngroupsS + 3) / 4, 256, 0, stream>>>(
        feats, pcd, b_in, (const half8*)wAf, Sb, N);

    int ngroups = (E + 15) / 16;
    edge_mfma<<<2048, 256, 0, stream>>>(Sb, also_pts, row, col, labels,
                                        (const half8*)w1f, (const half8*)wpf,
                                        (const unsigned*)w0h, (const unsigned*)w1h,
                                        (const unsigned*)b1h, bf,
                                        (float*)d_out, E, ngroups);
}